// Round 2
// baseline (359.390 us; speedup 1.0000x reference)
//
#include <hip/hip_runtime.h>
#include <hip/hip_fp16.h>

#define DEV __device__ __forceinline__

using half8 = __attribute__((ext_vector_type(8))) _Float16;
using half4 = __attribute__((ext_vector_type(4))) _Float16;
using f32x4 = __attribute__((ext_vector_type(4))) float;

// async global->LDS, 16B per lane. LDS dest is wave-uniform base + lane*16B.
DEV void gload_lds16(const void* g, void* l) {
  __builtin_amdgcn_global_load_lds((const __attribute__((address_space(1))) unsigned int*)g,
                                   (__attribute__((address_space(3))) unsigned int*)l,
                                   16, 0, 0);
}

DEV f32x4 mfma16x32(half8 a, half8 b, f32x4 c) {
  return __builtin_amdgcn_mfma_f32_16x16x32_f16(a, b, c, 0, 0, 0);
}

// ---------------- f32 -> f16, 3 buffers in one launch (z selects) ----------------
// now only used for the small weight matrices (3 x 1M elems)
__global__ void conv3_f32_f16(const float* __restrict__ s0, const float* __restrict__ s1,
                              const float* __restrict__ s2, _Float16* __restrict__ d0,
                              _Float16* __restrict__ d1, _Float16* __restrict__ d2, int n) {
  const float* s = blockIdx.z == 0 ? s0 : (blockIdx.z == 1 ? s1 : s2);
  _Float16* d = blockIdx.z == 0 ? d0 : (blockIdx.z == 1 ? d1 : d2);
  int i = (blockIdx.x * 256 + threadIdx.x) * 8;
  if (i >= n) return;
  float4 a = *(const float4*)(s + i);
  float4 b = *(const float4*)(s + i + 4);
  half8 h;
  h[0] = (_Float16)a.x; h[1] = (_Float16)a.y; h[2] = (_Float16)a.z; h[3] = (_Float16)a.w;
  h[4] = (_Float16)b.x; h[5] = (_Float16)b.y; h[6] = (_Float16)b.z; h[7] = (_Float16)b.w;
  *(half8*)(d + i) = h;
}

// ---------------- relative-position bias rp[s][t] ----------------
__global__ __launch_bounds__(192) void rp_kernel(const float* __restrict__ Wlin,
                                                 const float* __restrict__ wg,
                                                 float* __restrict__ rp) {
  int s = blockIdx.x, t = threadIdx.x;
  if (t >= 144) return;
  int rs = s / 12, cs = s % 12, rt = t / 12, ct = t % 12;
  float dx = (cs - ct) / 12.f, dy = (rs - rt) / 12.f;
  float ax = (dx > 0.f) ? 0.5f : (dx < 0.f ? -0.5f : 0.f);
  float ay = (dy > 0.f) ? 0.5f : (dy < 0.f ? -0.5f : 0.f);
  float lx = fabsf(logf(fabsf(dx) + 0.5f));
  float ly = fabsf(logf(fabsf(dy) + 0.5f));
  float a0 = 0.f, a1 = 0.f, a2 = 0.f, a3 = 0.f;
  const float* wgs = wg + s * 1024;
  for (int d = 0; d < 1024; d += 4) {
#pragma unroll
    for (int u = 0; u < 4; ++u) {
      float4 w = *(const float4*)(Wlin + (d + u) * 4);
      float dot = lx * w.x + ly * w.y + ax * w.z + ay * w.w;
      dot = dot > 0.f ? dot : 0.f;
      float p = dot * wgs[d + u];
      if (u == 0) a0 += p; else if (u == 1) a1 += p; else if (u == 2) a2 += p; else a3 += p;
    }
  }
  float acc = (a0 + a1) + (a2 + a3);
  rp[s * 144 + t] = acc > 0.f ? acc : 0.f;
}

// ---------------- projection GEMM: C = relu(A32 * B^T + bias), A f32 / W f16 / C f16 ----
// Proven r4 structure (256x128 block, 4 waves, wave-tile 128x64, BK=32, triple-buffer
// depth-2) with the f32->f16 conversion of A FUSED into staging:
//   A path: global_load_dwordx4 x2 (f32, rotated source) -> cvt -> ds_write_b128
//   B path: gload_lds16 (weights preconverted to f16 by small conv3)
// LDS layout identical to r4 (24 chunks x 1KB per slot), so fragment reads + MFMA loop
// are byte-identical. FIFO per iter: [A8 regs pre-barrier][B2 gload post-barrier];
// counted vmcnt(10) retires cur-slot B (issued t-2) + regsCur A (loaded t-1).
// ds_writes drained by lgkmcnt(0) pre-barrier; stage writes (ISSUEB/DSWRITE) only
// post-barrier -> no read clobber at wave skew 1 (same invariant as r4).
__global__ __launch_bounds__(256, 2) void gemm_proj(
    const float* __restrict__ A0, const float* __restrict__ A1,
    const float* __restrict__ A2, const _Float16* __restrict__ w0q,
    const _Float16* __restrict__ w1q, const _Float16* __restrict__ w2q,
    const float* __restrict__ bi0, const float* __restrict__ bi1,
    const float* __restrict__ bi2, _Float16* __restrict__ c0q,
    _Float16* __restrict__ c1q, _Float16* __restrict__ c2q) {
  const float* A = blockIdx.z == 0 ? A0 : (blockIdx.z == 1 ? A1 : A2);
  const _Float16* W = blockIdx.z == 0 ? w0q : (blockIdx.z == 1 ? w1q : w2q);
  const float* bias = blockIdx.z == 0 ? bi0 : (blockIdx.z == 1 ? bi1 : bi2);
  _Float16* C = blockIdx.z == 0 ? c0q : (blockIdx.z == 1 ? c1q : c2q);

  __shared__ __align__(16) char lds[73728];  // 3 x 24KB slots (A 16KB + B 8KB each)
  int tid = threadIdx.x, wid = tid >> 6, lane = tid & 63;
  int lin = blockIdx.y * 8 + blockIdx.x;     // 0..575 ; XCD-chunked, 72 per XCD
  int local = lin >> 3;
  int mt = (lin & 7) * 9 + (local >> 3), nt = local & 7;
  int m0 = mt * 256, n0 = nt * 128;

  int r4l = lane >> 2, c4 = lane & 3;
  int cg8 = ((c4 + (r4l >> 1)) & 3) * 8;                 // rotated source kslot (elems)
  int lr = lane & 15, lg = lane >> 4;
  int rdoff = lr * 64 + ((lg - (lr >> 1)) & 3) * 16;     // fragment read offset (bytes)

  // A: wave stages chunks c*4+wid, c=0..3 (rows m0 + chunk*16 + r4l), f32 source.
  const float* pA[4];
#pragma unroll
  for (int c = 0; c < 4; ++c)
    pA[c] = A + (size_t)(m0 + (c * 4 + wid) * 16 + r4l) * 1024 + cg8;
  // B: wave stages chunks 16 + c*4 + wid, c=0..1 (rows n0 + (c*4+wid)*16 + r4l), f16.
  const _Float16* pB[2];
#pragma unroll
  for (int c = 0; c < 2; ++c)
    pB[c] = W + (size_t)(n0 + (c * 4 + wid) * 16 + r4l) * 1024 + cg8;

  char *sl0 = lds, *sl1 = lds + 24576, *sl2 = lds + 49152;

#define LOADA(RG, TT) do { int kk_ = ((TT) < 32 ? (TT) : 31) * 32;             \
    _Pragma("unroll") for (int c = 0; c < 4; ++c) {                            \
      RG[c * 2]     = *(const float4*)(pA[c] + kk_);                           \
      RG[c * 2 + 1] = *(const float4*)(pA[c] + kk_ + 4);                       \
    } } while (0)

#define ISSUEB(TT, SLOT) do { int kk_ = ((TT) < 32 ? (TT) : 31) * 32;          \
    _Pragma("unroll") for (int c = 0; c < 2; ++c)                              \
      gload_lds16(pB[c] + kk_, (SLOT) + (16 + c * 4 + wid) * 1024);            \
    } while (0)

#define DSWRITE(RG, SLOT) do {                                                 \
    _Pragma("unroll") for (int c = 0; c < 4; ++c) {                            \
      half8 h_;                                                                \
      h_[0] = (_Float16)RG[c * 2].x;     h_[1] = (_Float16)RG[c * 2].y;        \
      h_[2] = (_Float16)RG[c * 2].z;     h_[3] = (_Float16)RG[c * 2].w;        \
      h_[4] = (_Float16)RG[c * 2 + 1].x; h_[5] = (_Float16)RG[c * 2 + 1].y;    \
      h_[6] = (_Float16)RG[c * 2 + 1].z; h_[7] = (_Float16)RG[c * 2 + 1].w;    \
      *(half8*)((SLOT) + (c * 4 + wid) * 1024 + lane * 16) = h_;               \
    } } while (0)

  // prologue: tile0 fully staged; rB <- A(tile1); B(tile1) in flight to sl1.
  float4 rA[8], rB[8];
  LOADA(rA, 0);
  ISSUEB(0, sl0);
  asm volatile("s_waitcnt vmcnt(0)" ::: "memory");
  DSWRITE(rA, sl0);
  LOADA(rB, 1);
  ISSUEB(1, sl1);
  f32x4 acc[8][4] = {};
  int abase = (wid >> 1) * 8192, bbase = 16384 + (wid & 1) * 4096;

#define GBODY(REGC, REGN, T) do {                                              \
    LOADA(REGN, (T) + 2);                                                      \
    asm volatile("s_waitcnt vmcnt(10)" ::: "memory");                          \
    asm volatile("s_waitcnt lgkmcnt(0)" ::: "memory");                         \
    __builtin_amdgcn_sched_barrier(0);                                         \
    __builtin_amdgcn_s_barrier();                                              \
    __builtin_amdgcn_sched_barrier(0);                                         \
    ISSUEB((T) + 2, sl2);                                                      \
    half8 a_[8], b_[4];                                                        \
    _Pragma("unroll") for (int i = 0; i < 8; ++i)                              \
      a_[i] = *(const half8*)(sl0 + abase + i * 1024 + rdoff);                 \
    _Pragma("unroll") for (int j = 0; j < 4; ++j)                              \
      b_[j] = *(const half8*)(sl0 + bbase + j * 1024 + rdoff);                 \
    DSWRITE(REGC, sl1);                                                        \
    _Pragma("unroll") for (int i = 0; i < 8; ++i)                              \
      _Pragma("unroll") for (int j = 0; j < 4; ++j)                            \
        acc[i][j] = mfma16x32(b_[j], a_[i], acc[i][j]);  /* swapped */         \
    char* tmp_ = sl0; sl0 = sl1; sl1 = sl2; sl2 = tmp_;                        \
  } while (0)

  for (int tp = 0; tp < 16; ++tp) {
    GBODY(rB, rA, 2 * tp);
    GBODY(rA, rB, 2 * tp + 1);
  }
#undef GBODY
#undef DSWRITE
#undef ISSUEB
#undef LOADA

  // epilogue: bias + relu -> f16, 8B vector stores
  int wm = (wid >> 1) * 128, wn = (wid & 1) * 64;
#pragma unroll
  for (int i = 0; i < 8; ++i) {
    int row = m0 + wm + i * 16 + lr;
#pragma unroll
    for (int j = 0; j < 4; ++j) {
      int col = n0 + wn + j * 16 + lg * 4;
      float4 b4 = *(const float4*)(bias + col);
      half4 h;
      float v0 = acc[i][j][0] + b4.x; h[0] = (_Float16)(v0 > 0.f ? v0 : 0.f);
      float v1 = acc[i][j][1] + b4.y; h[1] = (_Float16)(v1 > 0.f ? v1 : 0.f);
      float v2 = acc[i][j][2] + b4.z; h[2] = (_Float16)(v2 > 0.f ? v2 : 0.f);
      float v3 = acc[i][j][3] + b4.w; h[3] = (_Float16)(v3 > 0.f ? v3 : 0.f);
      *(half4*)(C + (size_t)row * 1024 + col) = h;
    }
  }
}

// ---------------- transpose v_proj [b*144+s][e] -> vt [b*1024+e][160] (zero-padded) ----
__global__ __launch_bounds__(256) void transpose_v(const _Float16* __restrict__ v,
                                                   _Float16* __restrict__ vt) {
  __shared__ _Float16 t[64][65];
  int b = blockIdx.z, e0 = blockIdx.x * 64, s0 = blockIdx.y * 64;
  int c = threadIdx.x & 63, r4 = threadIdx.x >> 6;
#pragma unroll
  for (int p = 0; p < 16; ++p) {
    int r = p * 4 + r4;
    t[r][c] = (s0 + r < 144) ? v[(size_t)(b * 144 + s0 + r) * 1024 + e0 + c] : (_Float16)0.f;
  }
  __syncthreads();
#pragma unroll
  for (int p = 0; p < 16; ++p) {
    int i = p * 4 + r4;
    if (s0 + c < 160) vt[(size_t)(b * 1024 + e0 + i) * 160 + s0 + c] = t[c][i];
  }
}

// ---------------- fused attention per (batch, 48-row third) ----------------
// q,k [18432][1024] f16 ; vt [b*1024+e][160] f16 zero-padded ; rp [144][144] f32
__global__ __launch_bounds__(256) void attn_kernel(const _Float16* __restrict__ q,
                                                   const _Float16* __restrict__ k,
                                                   const _Float16* __restrict__ vt,
                                                   const float* __restrict__ rp,
                                                   float* __restrict__ out) {
  __shared__ __align__(16) char lds[53248];
  // phase1 slots: 0 / 12288 / 24576 (12KB) ; phase2 slots: 0 / 16384 (16KB)
  // sc (f32, stride 152) aliases 0..29184 ; P @36864 (48x168 f16) ; sums @52992
  float* sc = (float*)lds;
  _Float16* P = (_Float16*)(lds + 36864);
  float* sums = (float*)(lds + 52992);

  int tid = threadIdx.x, wid = tid >> 6, lane = tid & 63;
  int lin = blockIdx.y * 3 + blockIdx.x;       // 0..383
  int swz = (lin & 7) * 48 + (lin >> 3);
  int mt3 = swz % 3, b = swz / 3;
  int m0 = mt3 * 48;
  const int nstart_t[4] = {0, 3, 5, 7};
  const int ncnt_t[4]   = {3, 2, 2, 2};
  int ns = nstart_t[wid], nc = ncnt_t[wid];
  int r4l = lane >> 2, c4 = lane & 3;
  int cg8 = ((c4 + (r4l >> 1)) & 3) * 8;
  int lr = lane & 15, lg = lane >> 4;
  int rdoff = lr * 64 + ((lg - (lr >> 1)) & 3) * 16;   // bytes

  // ---- phase 1: scores = q . k^T over K=1024, triple-buffer depth-2 ----
  {
    char *sl0 = lds, *sl1 = lds + 12288, *sl2 = lds + 24576;
    const _Float16* g1[3];
#pragma unroll
    for (int c = 0; c < 3; ++c) {
      int qq = c * 4 + wid;  // 0..2 -> q chunks (48 rows), 3..11 -> k chunks (144 rows)
      g1[c] = (qq < 3) ? q + (size_t)(b * 144 + m0 + qq * 16 + r4l) * 1024 + cg8
                       : k + (size_t)(b * 144 + (qq - 3) * 16 + r4l) * 1024 + cg8;
    }
    auto issue1 = [&](char* slot) {
#pragma unroll
      for (int c = 0; c < 3; ++c) {
        gload_lds16(g1[c], slot + (c * 4 + wid) * 1024);
        g1[c] += 32;
      }
    };
    issue1(sl0);
    issue1(sl1);
    f32x4 acc[3][3] = {};
    for (int t = 0; t < 32; ++t) {
      asm volatile("s_waitcnt vmcnt(3)" ::: "memory");
      __builtin_amdgcn_sched_barrier(0);
      __builtin_amdgcn_s_barrier();
      __builtin_amdgcn_sched_barrier(0);
      issue1(sl2);  // tail garbage stays inside qp/kp/vp
      half8 af[3], bf[3];
#pragma unroll
      for (int i = 0; i < 3; ++i)
        af[i] = *(const half8*)(sl0 + i * 1024 + rdoff);
#pragma unroll
      for (int j = 0; j < 3; ++j)
        if (j < nc)
          bf[j] = *(const half8*)(sl0 + (3 + ns + j) * 1024 + rdoff);
#pragma unroll
      for (int i = 0; i < 3; ++i)
#pragma unroll
        for (int j = 0; j < 3; ++j)
          if (j < nc)
            acc[i][j] = mfma16x32(bf[j], af[i], acc[i][j]);  // swapped
      char* tmp = sl0; sl0 = sl1; sl1 = sl2; sl2 = tmp;
    }
    asm volatile("s_waitcnt vmcnt(0)" ::: "memory");
    __syncthreads();  // straggler prefetches drained before sc aliases the slots
    const float scale = 0.03125f;  // 1024^-0.5
#pragma unroll
    for (int i = 0; i < 3; ++i) {
      int qrow = i * 16 + lr;
#pragma unroll
      for (int j = 0; j < 3; ++j)
        if (j < nc) {
          int kc0 = (ns + j) * 16 + lg * 4;
          float4 rr = *(const float4*)(rp + (m0 + qrow) * 144 + kc0);
          f32x4 vs;
          vs[0] = acc[i][j][0] * scale + rr.x;
          vs[1] = acc[i][j][1] * scale + rr.y;
          vs[2] = acc[i][j][2] * scale + rr.z;
          vs[3] = acc[i][j][3] * scale + rr.w;
          *(f32x4*)(sc + qrow * 152 + kc0) = vs;
        }
    }
  }
  __syncthreads();

  // ---- softmax (unnormalized; sums kept for epilogue) ----
  if (tid < 192) {
    int r = tid >> 2, qd = tid & 3;
    int cb = qd * 36;
    float m = -1e30f;
    for (int c2 = 0; c2 < 36; ++c2) m = fmaxf(m, sc[r * 152 + cb + c2]);
    m = fmaxf(m, __shfl_xor(m, 1));
    m = fmaxf(m, __shfl_xor(m, 2));
    float s = 0.f;
    for (int c2 = 0; c2 < 36; ++c2) {
      float e = __expf(sc[r * 152 + cb + c2] - m);
      s += e;
      P[r * 168 + cb + c2] = (_Float16)e;
    }
    s += __shfl_xor(s, 1);
    s += __shfl_xor(s, 2);
    if (qd == 0) sums[r] = s;
  }
  if (tid < 96) {  // zero-pad P cols 144..159
    int r = tid >> 1, c0 = 144 + (tid & 1) * 8;
    *(half8*)(P + r * 168 + c0) = (half8){};
  }
  __syncthreads();

  // ---- phase 2: out = (P @ V) / sums — 20 uniform K=32 iters, 2 slots depth-1 ----
  char *s0p = lds, *s1p = lds + 16384;
  auto issue2 = [&](int idx, char* slot) {
    int nn0 = (idx / 5) * 256, kk0 = (idx % 5) * 32;
#pragma unroll
    for (int c = 0; c < 4; ++c) {
      int ch = c * 4 + wid;  // 16 chunks of 16 rows
      gload_lds16(vt + (size_t)(b * 1024 + nn0 + ch * 16 + r4l) * 160 + kk0 + cg8,
                  slot + ch * 1024);
    }
  };
  issue2(0, s0p);
  f32x4 o[3][4] = {};
  for (int it = 0; it < 20; ++it) {
    asm volatile("s_waitcnt vmcnt(0)" ::: "memory");
    __builtin_amdgcn_sched_barrier(0);
    __builtin_amdgcn_s_barrier();
    __builtin_amdgcn_sched_barrier(0);
    issue2(it + 1, ((it + 1) & 1) ? s1p : s0p);  // it=19 -> garbage into the pad after vt
    char* sb = (it & 1) ? s1p : s0p;
    int k0 = (it % 5) * 32;
    half8 af[3], bf[4];
#pragma unroll
    for (int i = 0; i < 3; ++i)
      af[i] = *(const half8*)(P + (i * 16 + lr) * 168 + k0 + lg * 8);
#pragma unroll
    for (int j = 0; j < 4; ++j)
      bf[j] = *(const half8*)(sb + (wid * 4 + j) * 1024 + rdoff);
#pragma unroll
    for (int i = 0; i < 3; ++i)
#pragma unroll
      for (int j = 0; j < 4; ++j)
        o[i][j] = mfma16x32(bf[j], af[i], o[i][j]);  // swapped
    if (it % 5 == 4) {
      int n0 = (it / 5) * 256;
#pragma unroll
      for (int i = 0; i < 3; ++i) {
        int row = i * 16 + lr;
        float inv = 1.f / sums[row];
#pragma unroll
        for (int j = 0; j < 4; ++j) {
          f32x4 vo;
          vo[0] = o[i][j][0] * inv; vo[1] = o[i][j][1] * inv;
          vo[2] = o[i][j][2] * inv; vo[3] = o[i][j][3] * inv;
          *(f32x4*)(out + (size_t)(b * 144 + m0 + row) * 1024 + n0 + wid * 64 + j * 16 + lg * 4) = vo;
          o[i][j] = (f32x4){};
        }
      }
    }
  }
}

extern "C" void kernel_launch(void* const* d_in, const int* in_sizes, int n_in,
                              void* d_out, int out_size, void* d_ws, size_t ws_size,
                              hipStream_t stream) {
  const float* query = (const float*)d_in[0];
  const float* key   = (const float*)d_in[1];
  const float* value = (const float*)d_in[2];
  const float* Wq    = (const float*)d_in[3];
  const float* bq    = (const float*)d_in[4];
  const float* Wk    = (const float*)d_in[5];
  const float* bk    = (const float*)d_in[6];
  const float* Wv    = (const float*)d_in[7];
  const float* bv    = (const float*)d_in[8];
  const float* Wlin  = (const float*)d_in[9];
  const float* wg    = (const float*)d_in[10];
  float* out = (float*)d_out;

  char* ws = (char*)d_ws;
  const size_t NQKV = (size_t)18432 * 1024;            // 37.75 MB as f16
  const size_t NVT  = (size_t)131072 * 160;            // padded vt (40 MB)
  const int    NW   = 1024 * 1024;
  _Float16* Wqb = (_Float16*)(ws);
  _Float16* Wkb = (_Float16*)(ws + (2u << 20));
  _Float16* Wvb = (_Float16*)(ws + (4u << 20));
  _Float16* qp  = (_Float16*)(ws + (6u << 20));
  _Float16* kp  = qp + NQKV;
  _Float16* vp  = kp + NQKV;
  _Float16* vt  = vp + NQKV;                           // 40MB
  float*    rp  = (float*)((char*)(vt + NVT) + 65536);
  // total ws use: 6MB + 3*37.75MB + 40MB + guard + 83KB  ~= 160MB

  dim3 tgrid(16, 3, 128), agrid(3, 128);

  // fused path: gemm_proj reads f32 inputs directly (A-staging converts in-kernel);
  // only the small weight matrices get a conversion pass.
  conv3_f32_f16<<<dim3(NW / 2048, 1, 3), 256, 0, stream>>>(Wq, Wk, Wv, Wqb, Wkb, Wvb, NW);
  rp_kernel<<<144, 192, 0, stream>>>(Wlin, wg, rp);
  gemm_proj<<<dim3(8, 72, 3), 256, 0, stream>>>(query, key, value, Wqb, Wkb, Wvb,
                                                bq, bk, bv, qp, kp, vp);
  transpose_v<<<tgrid, 256, 0, stream>>>(vp, vt);
  attn_kernel<<<agrid, 256, 0, stream>>>(qp, kp, vt, rp, out);
}

// Round 3
// 319.318 us; speedup vs baseline: 1.1255x; 1.1255x over previous
//
#include <hip/hip_runtime.h>
#include <hip/hip_fp16.h>

#define DEV __device__ __forceinline__

using half8 = __attribute__((ext_vector_type(8))) _Float16;
using half4 = __attribute__((ext_vector_type(4))) _Float16;
using f32x4 = __attribute__((ext_vector_type(4))) float;

// async global->LDS, 16B per lane. LDS dest is wave-uniform base + lane*16B.
DEV void gload_lds16(const void* g, void* l) {
  __builtin_amdgcn_global_load_lds((const __attribute__((address_space(1))) unsigned int*)g,
                                   (__attribute__((address_space(3))) unsigned int*)l,
                                   16, 0, 0);
}

DEV f32x4 mfma16x32(half8 a, half8 b, f32x4 c) {
  return __builtin_amdgcn_mfma_f32_16x16x32_f16(a, b, c, 0, 0, 0);
}

// ---------------- f32 -> f16, 3 buffers in one launch (z selects) ----------------
__global__ void conv3_f32_f16(const float* __restrict__ s0, const float* __restrict__ s1,
                              const float* __restrict__ s2, _Float16* __restrict__ d0,
                              _Float16* __restrict__ d1, _Float16* __restrict__ d2, int n) {
  const float* s = blockIdx.z == 0 ? s0 : (blockIdx.z == 1 ? s1 : s2);
  _Float16* d = blockIdx.z == 0 ? d0 : (blockIdx.z == 1 ? d1 : d2);
  int i = (blockIdx.x * 256 + threadIdx.x) * 8;
  if (i >= n) return;
  float4 a = *(const float4*)(s + i);
  float4 b = *(const float4*)(s + i + 4);
  half8 h;
  h[0] = (_Float16)a.x; h[1] = (_Float16)a.y; h[2] = (_Float16)a.z; h[3] = (_Float16)a.w;
  h[4] = (_Float16)b.x; h[5] = (_Float16)b.y; h[6] = (_Float16)b.z; h[7] = (_Float16)b.w;
  *(half8*)(d + i) = h;
}

// ---------------- zero vt pad columns s=144..159 (must be finite for PV) -------------
__global__ void vt_pad_zero(_Float16* __restrict__ vt) {
  int i = blockIdx.x * 256 + threadIdx.x;   // 131072 (b,e) rows
  _Float16* p = vt + (size_t)i * 160 + 144;
  *(half8*)p = (half8){};
  *(half8*)(p + 8) = (half8){};
}

// ---------------- relative-position bias rp[s][t] ----------------
__global__ __launch_bounds__(192) void rp_kernel(const float* __restrict__ Wlin,
                                                 const float* __restrict__ wg,
                                                 float* __restrict__ rp) {
  int s = blockIdx.x, t = threadIdx.x;
  if (t >= 144) return;
  int rs = s / 12, cs = s % 12, rt = t / 12, ct = t % 12;
  float dx = (cs - ct) / 12.f, dy = (rs - rt) / 12.f;
  float ax = (dx > 0.f) ? 0.5f : (dx < 0.f ? -0.5f : 0.f);
  float ay = (dy > 0.f) ? 0.5f : (dy < 0.f ? -0.5f : 0.f);
  float lx = fabsf(logf(fabsf(dx) + 0.5f));
  float ly = fabsf(logf(fabsf(dy) + 0.5f));
  float a0 = 0.f, a1 = 0.f, a2 = 0.f, a3 = 0.f;
  const float* wgs = wg + s * 1024;
  for (int d = 0; d < 1024; d += 4) {
#pragma unroll
    for (int u = 0; u < 4; ++u) {
      float4 w = *(const float4*)(Wlin + (d + u) * 4);
      float dot = lx * w.x + ly * w.y + ax * w.z + ay * w.w;
      dot = dot > 0.f ? dot : 0.f;
      float p = dot * wgs[d + u];
      if (u == 0) a0 += p; else if (u == 1) a1 += p; else if (u == 2) a2 += p; else a3 += p;
    }
  }
  float acc = (a0 + a1) + (a2 + a3);
  rp[s * 144 + t] = acc > 0.f ? acc : 0.f;
}

// ---------------- projection GEMM: C = relu(A * B^T + bias), f16 in/out ----------------
// 256(M)x128(N) block, 4 waves, wave-tile 128x64 (acc 8x4), BK=32.  (r4-proven, R0)
// All staging via gload_lds16 chunks (16 rows x 32 f16 = 1KB), rotation-swizzled source
// (coalesced 64B lines + conflict-free fragment reads).
// Triple buffer, depth-2 prefetch, counted vmcnt(6). blockIdx.z selects matrix triple.
// z == vtz additionally writes the TRANSPOSED output into vt[(b*1024+e)*160+s]
// (replaces the separate transpose_v pass; C is not written for that z).
__global__ __launch_bounds__(256, 2) void gemm_proj(
    const _Float16* __restrict__ a0q, const _Float16* __restrict__ a1q,
    const _Float16* __restrict__ a2q, const _Float16* __restrict__ w0q,
    const _Float16* __restrict__ w1q, const _Float16* __restrict__ w2q,
    const float* __restrict__ bi0, const float* __restrict__ bi1,
    const float* __restrict__ bi2, _Float16* __restrict__ c0q,
    _Float16* __restrict__ c1q, _Float16* __restrict__ c2q,
    _Float16* __restrict__ vtp, int vtz) {
  const _Float16* A = blockIdx.z == 0 ? a0q : (blockIdx.z == 1 ? a1q : a2q);
  const _Float16* W = blockIdx.z == 0 ? w0q : (blockIdx.z == 1 ? w1q : w2q);
  const float* bias = blockIdx.z == 0 ? bi0 : (blockIdx.z == 1 ? bi1 : bi2);
  _Float16* C = blockIdx.z == 0 ? c0q : (blockIdx.z == 1 ? c1q : c2q);

  __shared__ __align__(16) char lds[73728];  // 3 x 24KB slots (A 16KB + B 8KB each)
  int tid = threadIdx.x, wid = tid >> 6, lane = tid & 63;
  int lin = blockIdx.y * 8 + blockIdx.x;     // 0..575 ; XCD-chunked, 72 per XCD
  int local = lin >> 3;
  int mt = (lin & 7) * 9 + (local >> 3), nt = local & 7;
  int m0 = mt * 256, n0 = nt * 128;

  int r4l = lane >> 2, c4 = lane & 3;
  int cg8 = ((c4 + (r4l >> 1)) & 3) * 8;                 // rotated source kslot (f16)
  int lr = lane & 15, lg = lane >> 4;
  int rdoff = lr * 64 + ((lg - (lr >> 1)) & 3) * 16;     // fragment read offset (bytes)

  // 24 chunks: 0..15 A rows m0+q*16, 16..23 B rows n0+(q-16)*16. Wave w stages c*4+w.
  const _Float16* gp[6];
#pragma unroll
  for (int c = 0; c < 6; ++c) {
    int q = c * 4 + wid;
    gp[c] = (q < 16) ? A + (size_t)(m0 + q * 16 + r4l) * 1024 + cg8
                     : W + (size_t)(n0 + (q - 16) * 16 + r4l) * 1024 + cg8;
  }
  char *sl0 = lds, *sl1 = lds + 24576, *sl2 = lds + 49152;
  auto issue = [&](char* slot) {
#pragma unroll
    for (int c = 0; c < 6; ++c) { gload_lds16(gp[c], slot + (c * 4 + wid) * 1024); gp[c] += 32; }
  };
  issue(sl0);
  issue(sl1);
  f32x4 acc[8][4] = {};
  int abase = (wid >> 1) * 8192, bbase = 16384 + (wid & 1) * 4096;
  for (int t = 0; t < 32; ++t) {
    asm volatile("s_waitcnt vmcnt(6)" ::: "memory");
    __builtin_amdgcn_s_barrier();
    __builtin_amdgcn_sched_barrier(0);
    issue(sl2);  // unconditional; tail prefetch reads in-bounds garbage (ws interior)
    half8 a[8], b[4];
#pragma unroll
    for (int i = 0; i < 8; ++i) a[i] = *(const half8*)(sl0 + abase + i * 1024 + rdoff);
#pragma unroll
    for (int j = 0; j < 4; ++j) b[j] = *(const half8*)(sl0 + bbase + j * 1024 + rdoff);
#pragma unroll
    for (int i = 0; i < 8; ++i)
#pragma unroll
      for (int j = 0; j < 4; ++j)
        acc[i][j] = mfma16x32(b[j], a[i], acc[i][j]);  // swapped: lane holds 4 consec cols
    char* tmp = sl0; sl0 = sl1; sl1 = sl2; sl2 = tmp;
  }
  // epilogue: bias + relu -> f16. Normal z: 8B vector stores to C.
  // z == vtz: transposed scatter into vt (16-consecutive-s x 2B = 32B segments).
  int wm = (wid >> 1) * 128, wn = (wid & 1) * 64;
  bool tov = (vtp != nullptr) && ((int)blockIdx.z == vtz);
#pragma unroll
  for (int i = 0; i < 8; ++i) {
    int row = m0 + wm + i * 16 + lr;
#pragma unroll
    for (int j = 0; j < 4; ++j) {
      int col = n0 + wn + j * 16 + lg * 4;
      float4 b4 = *(const float4*)(bias + col);
      half4 h;
      float v0 = acc[i][j][0] + b4.x; h[0] = (_Float16)(v0 > 0.f ? v0 : 0.f);
      float v1 = acc[i][j][1] + b4.y; h[1] = (_Float16)(v1 > 0.f ? v1 : 0.f);
      float v2 = acc[i][j][2] + b4.z; h[2] = (_Float16)(v2 > 0.f ? v2 : 0.f);
      float v3 = acc[i][j][3] + b4.w; h[3] = (_Float16)(v3 > 0.f ? v3 : 0.f);
      if (tov) {
        int bb = row / 144, ss = row - bb * 144;
        _Float16* vb = vtp + (size_t)(bb * 1024 + col) * 160 + ss;
        vb[0] = h[0]; vb[160] = h[1]; vb[320] = h[2]; vb[480] = h[3];
      } else {
        *(half4*)(C + (size_t)row * 1024 + col) = h;
      }
    }
  }
}

// ---------------- fused attention per (batch, 48-row third) ----------------
// q,k [18432][1024] f16 ; vt [b*1024+e][160] f16 (pad cols finite) ; rp [144][144] f32
__global__ __launch_bounds__(256) void attn_kernel(const _Float16* __restrict__ q,
                                                   const _Float16* __restrict__ k,
                                                   const _Float16* __restrict__ vt,
                                                   const float* __restrict__ rp,
                                                   float* __restrict__ out) {
  __shared__ __align__(16) char lds[53248];
  // phase1 slots: 0 / 12288 / 24576 (12KB) ; phase2 slots: 0 / 16384 (16KB)
  // sc (f32, stride 152) aliases 0..29184 ; P @36864 (48x168 f16) ; sums @52992
  float* sc = (float*)lds;
  _Float16* P = (_Float16*)(lds + 36864);
  float* sums = (float*)(lds + 52992);

  int tid = threadIdx.x, wid = tid >> 6, lane = tid & 63;
  int lin = blockIdx.y * 3 + blockIdx.x;       // 0..383
  int swz = (lin & 7) * 48 + (lin >> 3);
  int mt3 = swz % 3, b = swz / 3;
  int m0 = mt3 * 48;
  const int nstart_t[4] = {0, 3, 5, 7};
  const int ncnt_t[4]   = {3, 2, 2, 2};
  int ns = nstart_t[wid], nc = ncnt_t[wid];
  int r4l = lane >> 2, c4 = lane & 3;
  int cg8 = ((c4 + (r4l >> 1)) & 3) * 8;
  int lr = lane & 15, lg = lane >> 4;
  int rdoff = lr * 64 + ((lg - (lr >> 1)) & 3) * 16;   // bytes

  // ---- phase 1: scores = q . k^T over K=1024, triple-buffer depth-2 ----
  {
    char *sl0 = lds, *sl1 = lds + 12288, *sl2 = lds + 24576;
    const _Float16* g1[3];
#pragma unroll
    for (int c = 0; c < 3; ++c) {
      int qq = c * 4 + wid;  // 0..2 -> q chunks (48 rows), 3..11 -> k chunks (144 rows)
      g1[c] = (qq < 3) ? q + (size_t)(b * 144 + m0 + qq * 16 + r4l) * 1024 + cg8
                       : k + (size_t)(b * 144 + (qq - 3) * 16 + r4l) * 1024 + cg8;
    }
    auto issue1 = [&](char* slot) {
#pragma unroll
      for (int c = 0; c < 3; ++c) {
        gload_lds16(g1[c], slot + (c * 4 + wid) * 1024);
        g1[c] += 32;
      }
    };
    issue1(sl0);
    issue1(sl1);
    f32x4 acc[3][3] = {};
    for (int t = 0; t < 32; ++t) {
      asm volatile("s_waitcnt vmcnt(3)" ::: "memory");
      __builtin_amdgcn_sched_barrier(0);
      __builtin_amdgcn_s_barrier();
      __builtin_amdgcn_sched_barrier(0);
      issue1(sl2);  // tail garbage stays inside qp/kp/vt
      half8 af[3], bf[3];
#pragma unroll
      for (int i = 0; i < 3; ++i)
        af[i] = *(const half8*)(sl0 + i * 1024 + rdoff);
#pragma unroll
      for (int j = 0; j < 3; ++j)
        if (j < nc)
          bf[j] = *(const half8*)(sl0 + (3 + ns + j) * 1024 + rdoff);
#pragma unroll
      for (int i = 0; i < 3; ++i)
#pragma unroll
        for (int j = 0; j < 3; ++j)
          if (j < nc)
            acc[i][j] = mfma16x32(bf[j], af[i], acc[i][j]);  // swapped
      char* tmp = sl0; sl0 = sl1; sl1 = sl2; sl2 = tmp;
    }
    asm volatile("s_waitcnt vmcnt(0)" ::: "memory");
    __syncthreads();  // straggler prefetches drained before sc aliases the slots
    const float scale = 0.03125f;  // 1024^-0.5
#pragma unroll
    for (int i = 0; i < 3; ++i) {
      int qrow = i * 16 + lr;
#pragma unroll
      for (int j = 0; j < 3; ++j)
        if (j < nc) {
          int kc0 = (ns + j) * 16 + lg * 4;
          float4 rr = *(const float4*)(rp + (m0 + qrow) * 144 + kc0);
          f32x4 vs;
          vs[0] = acc[i][j][0] * scale + rr.x;
          vs[1] = acc[i][j][1] * scale + rr.y;
          vs[2] = acc[i][j][2] * scale + rr.z;
          vs[3] = acc[i][j][3] * scale + rr.w;
          *(f32x4*)(sc + qrow * 152 + kc0) = vs;
        }
    }
  }
  __syncthreads();

  // ---- softmax (unnormalized; sums kept for epilogue) ----
  if (tid < 192) {
    int r = tid >> 2, qd = tid & 3;
    int cb = qd * 36;
    float m = -1e30f;
    for (int c2 = 0; c2 < 36; ++c2) m = fmaxf(m, sc[r * 152 + cb + c2]);
    m = fmaxf(m, __shfl_xor(m, 1));
    m = fmaxf(m, __shfl_xor(m, 2));
    float s = 0.f;
    for (int c2 = 0; c2 < 36; ++c2) {
      float e = __expf(sc[r * 152 + cb + c2] - m);
      s += e;
      P[r * 168 + cb + c2] = (_Float16)e;
    }
    s += __shfl_xor(s, 1);
    s += __shfl_xor(s, 2);
    if (qd == 0) sums[r] = s;
  }
  if (tid < 96) {  // zero-pad P cols 144..159
    int r = tid >> 1, c0 = 144 + (tid & 1) * 8;
    *(half8*)(P + r * 168 + c0) = (half8){};
  }
  __syncthreads();

  // ---- phase 2: out = (P @ V) / sums — 20 uniform K=32 iters, 2 slots depth-1 ----
  char *s0p = lds, *s1p = lds + 16384;
  auto issue2 = [&](int idx, char* slot) {
    int nn0 = (idx / 5) * 256, kk0 = (idx % 5) * 32;
#pragma unroll
    for (int c = 0; c < 4; ++c) {
      int ch = c * 4 + wid;  // 16 chunks of 16 rows
      gload_lds16(vt + (size_t)(b * 1024 + nn0 + ch * 16 + r4l) * 160 + kk0 + cg8,
                  slot + ch * 1024);
    }
  };
  issue2(0, s0p);
  f32x4 o[3][4] = {};
  for (int it = 0; it < 20; ++it) {
    asm volatile("s_waitcnt vmcnt(0)" ::: "memory");
    __builtin_amdgcn_sched_barrier(0);
    __builtin_amdgcn_s_barrier();
    __builtin_amdgcn_sched_barrier(0);
    issue2(it + 1, ((it + 1) & 1) ? s1p : s0p);  // it=19 -> garbage into region after vt
    char* sb = (it & 1) ? s1p : s0p;
    int k0 = (it % 5) * 32;
    half8 af[3], bf[4];
#pragma unroll
    for (int i = 0; i < 3; ++i)
      af[i] = *(const half8*)(P + (i * 16 + lr) * 168 + k0 + lg * 8);
#pragma unroll
    for (int j = 0; j < 4; ++j)
      bf[j] = *(const half8*)(sb + (wid * 4 + j) * 1024 + rdoff);
#pragma unroll
    for (int i = 0; i < 3; ++i)
#pragma unroll
      for (int j = 0; j < 4; ++j)
        o[i][j] = mfma16x32(bf[j], af[i], o[i][j]);  // swapped
    if (it % 5 == 4) {
      int n0 = (it / 5) * 256;
#pragma unroll
      for (int i = 0; i < 3; ++i) {
        int row = i * 16 + lr;
        float inv = 1.f / sums[row];
#pragma unroll
        for (int j = 0; j < 4; ++j) {
          f32x4 vo;
          vo[0] = o[i][j][0] * inv; vo[1] = o[i][j][1] * inv;
          vo[2] = o[i][j][2] * inv; vo[3] = o[i][j][3] * inv;
          *(f32x4*)(out + (size_t)(b * 144 + m0 + row) * 1024 + n0 + wid * 64 + j * 16 + lg * 4) = vo;
          o[i][j] = (f32x4){};
        }
      }
    }
  }
}

extern "C" void kernel_launch(void* const* d_in, const int* in_sizes, int n_in,
                              void* d_out, int out_size, void* d_ws, size_t ws_size,
                              hipStream_t stream) {
  const float* query = (const float*)d_in[0];
  const float* key   = (const float*)d_in[1];
  const float* value = (const float*)d_in[2];
  const float* Wq    = (const float*)d_in[3];
  const float* bq    = (const float*)d_in[4];
  const float* Wk    = (const float*)d_in[5];
  const float* bk    = (const float*)d_in[6];
  const float* Wv    = (const float*)d_in[7];
  const float* bv    = (const float*)d_in[8];
  const float* Wlin  = (const float*)d_in[9];
  const float* wg    = (const float*)d_in[10];
  float* out = (float*)d_out;

  char* ws = (char*)d_ws;
  const size_t NQKV = (size_t)18432 * 1024;            // 37.75 MB as f16
  const size_t NVT  = (size_t)131072 * 160;            // padded vt (40 MB)
  const int    NW   = 1024 * 1024;
  // layout: [W 6MB][rp 128KB][qp][kp][vt 40MB][...path-specific]
  _Float16* Wqb = (_Float16*)(ws);
  _Float16* Wkb = (_Float16*)(ws + (2u << 20));
  _Float16* Wvb = (_Float16*)(ws + (4u << 20));
  float*    rp  = (float*)(ws + (6u << 20));
  _Float16* qp  = (_Float16*)(ws + (6u << 20) + 131072);
  _Float16* kp  = qp + NQKV;
  _Float16* vt  = kp + NQKV;                           // 40MB; written by gemm z==vtz

  dim3 agrid(3, 128);

  if (ws_size >= 238000000ull) {
    // parallel layout: all three f16 inputs live at once; one conv launch, one z=3 GEMM.
    // total: 6.125MB + 75.5 + 40 + 64KB guard + 113.25 = 237.1MB
    _Float16* ia = vt + NVT + 32768;   // 64KB guard (attn tail prefetch overrun lands here)
    _Float16* ib = ia + NQKV;
    _Float16* ic = ib + NQKV;
    conv3_f32_f16<<<dim3((int)(NQKV / 2048), 1, 3), 256, 0, stream>>>(
        query, key, value, ia, ib, ic, (int)NQKV);
    conv3_f32_f16<<<dim3(NW / 2048, 1, 3), 256, 0, stream>>>(Wq, Wk, Wv, Wqb, Wkb, Wvb, NW);
    rp_kernel<<<144, 192, 0, stream>>>(Wlin, wg, rp);
    vt_pad_zero<<<512, 256, 0, stream>>>(vt);
    gemm_proj<<<dim3(8, 72, 3), 256, 0, stream>>>(ia, ib, ic, Wqb, Wkb, Wvb,
                                                  bq, bk, bv, qp, kp, kp /*unused for z2*/,
                                                  vt, 2);
    attn_kernel<<<agrid, 256, 0, stream>>>(qp, kp, vt, rp, out);
  } else {
    // sequential layout: shared input buffer after vt. total: 161.6MB (r2-proven size)
    _Float16* inb = vt + NVT;          // also absorbs attn tail-prefetch overrun
    rp_kernel<<<144, 192, 0, stream>>>(Wlin, wg, rp);
    vt_pad_zero<<<512, 256, 0, stream>>>(vt);
    conv3_f32_f16<<<dim3(NW / 2048, 1, 3), 256, 0, stream>>>(Wq, Wk, Wv, Wqb, Wkb, Wvb, NW);
    conv3_f32_f16<<<dim3((int)(NQKV / 2048), 1, 1), 256, 0, stream>>>(
        query, query, query, inb, inb, inb, (int)NQKV);
    gemm_proj<<<dim3(8, 72, 1), 256, 0, stream>>>(inb, inb, inb, Wqb, Wqb, Wqb,
                                                  bq, bq, bq, qp, qp, qp, nullptr, -1);
    conv3_f32_f16<<<dim3((int)(NQKV / 2048), 1, 1), 256, 0, stream>>>(
        key, key, key, inb, inb, inb, (int)NQKV);
    gemm_proj<<<dim3(8, 72, 1), 256, 0, stream>>>(inb, inb, inb, Wkb, Wkb, Wkb,
                                                  bk, bk, bk, kp, kp, kp, nullptr, -1);
    conv3_f32_f16<<<dim3((int)(NQKV / 2048), 1, 1), 256, 0, stream>>>(
        value, value, value, inb, inb, inb, (int)NQKV);
    gemm_proj<<<dim3(8, 72, 1), 256, 0, stream>>>(inb, inb, inb, Wvb, Wvb, Wvb,
                                                  bv, bv, bv, qp /*unused*/, qp, qp,
                                                  vt, 0);
    attn_kernel<<<agrid, 256, 0, stream>>>(qp, kp, vt, rp, out);
  }
}